// Round 2
// baseline (191269.629 us; speedup 1.0000x reference)
//
#include <hip/hip_runtime.h>

constexpr int N_ = 4096;
constexpr int D_ = 64;
constexpr int O_ = 64;
constexpr int T_ = 4096;
constexpr float LEAK_ = 0.8f;
constexpr int NBLK = 256;   // blocks (1 per CU; all co-resident -> barrier safe)
constexpr int NTHR = 256;   // threads per block (4 waves)
constexpr int RPB = N_ / NBLK;  // 16 rows per block
constexpr int RPW = RPB / 4;    // 4 rows per wave

// Prep: transpose W_out's weight part into WoT[row][o] and extract bias col.
__global__ void esn_prep(const float* __restrict__ W_out,
                         float* __restrict__ WoT, float* __restrict__ bo) {
    int idx = blockIdx.x * blockDim.x + threadIdx.x;
    if (idx < N_ * O_) {
        int row = idx / O_;
        int o = idx - row * O_;
        WoT[idx] = W_out[o * (N_ + 1) + row];
    }
    if (idx < O_) bo[idx] = W_out[idx * (N_ + 1) + N_];
}

// Monotonic-counter grid barrier. All NBLK blocks are co-resident (grid ==
// CU count, 1 block/CU worst case 8/CU capacity), so spinning cannot deadlock.
__device__ __forceinline__ void grid_barrier(unsigned* cnt, unsigned target) {
    __threadfence();     // make this thread's prior global writes device-visible
    __syncthreads();     // everyone in block done writing
    if (threadIdx.x == 0) {
        __hip_atomic_fetch_add(cnt, 1u, __ATOMIC_ACQ_REL, __HIP_MEMORY_SCOPE_AGENT);
        while (__hip_atomic_load(cnt, __ATOMIC_ACQUIRE, __HIP_MEMORY_SCOPE_AGENT) < target)
            __builtin_amdgcn_s_sleep(1);
    }
    __syncthreads();
}

__global__ __launch_bounds__(NTHR) void esn_main(
    const float* __restrict__ inputs, const float* __restrict__ W,
    const float* __restrict__ W_in, const float* __restrict__ b,
    const float* __restrict__ WoT, const float* __restrict__ bo,
    float* __restrict__ y, unsigned* __restrict__ cnt,
    float* __restrict__ xbuf, float* __restrict__ partials)
{
    __shared__ float x_lds[N_];       // 16 KB: full state vector
    __shared__ float u_lds[D_];
    __shared__ float xnew_lds[RPB];
    const int tid = threadIdx.x;
    const int bid = blockIdx.x;
    const int wave = tid >> 6;
    const int lane = tid & 63;
    const int row0 = bid * RPB;

    for (int t = 0; t < T_; ++t) {
        // Reduce PREVIOUS step's y-partials (pipelined; blocks 0..63, wave 0).
        if (t > 0 && bid < O_ && wave == 0) {
            const float* p = partials + ((t - 1) & 1) * (O_ * NBLK) + bid * NBLK;
            float s = p[lane] + p[lane + 64] + p[lane + 128] + p[lane + 192];
            #pragma unroll
            for (int off = 32; off; off >>= 1) s += __shfl_xor(s, off);
            if (lane == 0) y[(t - 1) * O_ + bid] = s + bo[bid];
        }

        // Stage u_t and x_{t-1} into LDS.
        if (tid < D_) u_lds[tid] = inputs[t * D_ + tid];
        const float* xsrc = xbuf + ((t + 1) & 1) * N_;  // (t-1)&1 parity
        if (t == 0) {
            for (int i = tid; i < N_; i += NTHR) x_lds[i] = 0.f;
        } else {
            for (int i = tid; i < N_; i += NTHR) x_lds[i] = xsrc[i];
        }
        __syncthreads();

        // Dense matvec: each wave computes RPW rows with float4 coalesced loads.
        #pragma unroll
        for (int r = 0; r < RPW; ++r) {
            const int row = row0 + wave * RPW + r;
            const float4* Wr = (const float4*)(W + (size_t)row * N_);
            const float4* xv = (const float4*)x_lds;
            float acc = 0.f;
            #pragma unroll
            for (int i = 0; i < N_ / 4 / 64; ++i) {   // 16 iterations
                float4 w4 = Wr[lane + 64 * i];
                float4 x4 = xv[lane + 64 * i];
                acc += w4.x * x4.x + w4.y * x4.y + w4.z * x4.z + w4.w * x4.w;
            }
            // Fold W_in @ u into the same reduction (D == 64 == wave size).
            acc += W_in[row * D_ + lane] * u_lds[lane];
            #pragma unroll
            for (int off = 32; off; off >>= 1) acc += __shfl_xor(acc, off);
            if (lane == 0) {
                float pre = acc + b[row];
                float xo = x_lds[row];  // zero at t==0 (LDS zeroed)
                float xn = (1.f - LEAK_) * xo + LEAK_ * tanhf(pre);
                xbuf[(t & 1) * N_ + row] = xn;
                xnew_lds[wave * RPW + r] = xn;
            }
        }
        __syncthreads();

        // Per-block partial of y_t = Wo @ x_new (64 outputs, 16 rows each).
        if (tid < O_) {
            float s = 0.f;
            #pragma unroll
            for (int r = 0; r < RPB; ++r)
                s += WoT[(row0 + r) * O_ + tid] * xnew_lds[r];
            partials[(t & 1) * (O_ * NBLK) + tid * NBLK + bid] = s;
        }

        grid_barrier(cnt, (unsigned)(t + 1) * NBLK);
    }

    // Drain: reduce partials of the final step.
    if (bid < O_ && wave == 0) {
        const float* p = partials + ((T_ - 1) & 1) * (O_ * NBLK) + bid * NBLK;
        float s = p[lane] + p[lane + 64] + p[lane + 128] + p[lane + 192];
        #pragma unroll
        for (int off = 32; off; off >>= 1) s += __shfl_xor(s, off);
        if (lane == 0) y[(T_ - 1) * O_ + bid] = s + bo[bid];
    }
}

extern "C" void kernel_launch(void* const* d_in, const int* in_sizes, int n_in,
                              void* d_out, int out_size, void* d_ws, size_t ws_size,
                              hipStream_t stream) {
    const float* inputs = (const float*)d_in[0];
    const float* W      = (const float*)d_in[1];
    const float* W_in   = (const float*)d_in[2];
    const float* b      = (const float*)d_in[3];
    const float* W_out  = (const float*)d_in[4];
    float* y  = (float*)d_out;

    // Workspace layout: [0,256) barrier counter; then floats:
    // xbuf[2*N] | partials[2*O*NBLK] | WoT[N*O] | bo[O]
    unsigned* cnt  = (unsigned*)d_ws;
    float* fws     = (float*)((char*)d_ws + 256);
    float* xbuf     = fws;
    float* partials = xbuf + 2 * N_;
    float* WoT      = partials + 2 * O_ * NBLK;
    float* bo       = WoT + N_ * O_;

    hipMemsetAsync(d_ws, 0, 256, stream);  // reset barrier counter every call

    hipLaunchKernelGGL(esn_prep, dim3((N_ * O_ + NTHR - 1) / NTHR), dim3(NTHR),
                       0, stream, W_out, WoT, bo);

    hipLaunchKernelGGL(esn_main, dim3(NBLK), dim3(NTHR), 0, stream,
                       inputs, W, W_in, b, WoT, bo, y, cnt, xbuf, partials);
}

// Round 3
// 161848.132 us; speedup vs baseline: 1.1818x; 1.1818x over previous
//
#include <hip/hip_runtime.h>

constexpr int N_ = 4096;
constexpr int D_ = 64;
constexpr int O_ = 64;
constexpr int T_ = 4096;
constexpr float LEAK_ = 0.8f;
constexpr int NBLK = 256;   // blocks (1 per CU; all co-resident -> barrier safe)
constexpr int NTHR = 1024;  // 16 waves per block, 4 per SIMD
constexpr int RPB = N_ / NBLK;   // 16 rows per block
constexpr int NWAVE = NTHR / 64; // 16 waves; one row per wave

// Prep: transpose W_out's weight part into WoT[row][o] and extract bias col.
__global__ void esn_prep(const float* __restrict__ W_out,
                         float* __restrict__ WoT, float* __restrict__ bo) {
    int idx = blockIdx.x * blockDim.x + threadIdx.x;
    if (idx < N_ * O_) {
        int row = idx / O_;
        int o = idx - row * O_;
        WoT[idx] = W_out[o * (N_ + 1) + row];
    }
    if (idx < O_) bo[idx] = W_out[idx * (N_ + 1) + N_];
}

__device__ __forceinline__ unsigned ld_acq(const unsigned* p) {
    return __hip_atomic_load(p, __ATOMIC_ACQUIRE, __HIP_MEMORY_SCOPE_AGENT);
}
__device__ __forceinline__ void st_rel(unsigned* p, unsigned v) {
    __hip_atomic_store(p, v, __ATOMIC_RELEASE, __HIP_MEMORY_SCOPE_AGENT);
}

// Flag-tree grid barrier: per-block padded arrival flags (no RMW contention),
// block 0 gathers and publishes a single `go` word. All 256 blocks are
// co-resident (1 block/CU), so spinning cannot deadlock.
__device__ __forceinline__ void grid_barrier(unsigned* flags, unsigned* go,
                                             unsigned tgt) {
    __syncthreads();   // all threads of this block done with their writes
    if (blockIdx.x == 0) {
        if (threadIdx.x < NBLK) {
            if (threadIdx.x == 0) st_rel(&flags[0], tgt);
            // poll one flag per thread (flags padded to 128 B)
            while (ld_acq(&flags[threadIdx.x * 32]) < tgt)
                __builtin_amdgcn_s_sleep(2);
        }
        __syncthreads();
        if (threadIdx.x == 0) st_rel(go, tgt);
    } else {
        if (threadIdx.x == 0) {
            st_rel(&flags[blockIdx.x * 32], tgt);
            while (ld_acq(go) < tgt) __builtin_amdgcn_s_sleep(2);
        }
        __syncthreads();
    }
}

__global__ __launch_bounds__(NTHR) void esn_main(
    const float* __restrict__ inputs, const float* __restrict__ W,
    const float* __restrict__ W_in, const float* __restrict__ b,
    const float* __restrict__ WoT, const float* __restrict__ bo,
    float* __restrict__ y, unsigned* __restrict__ flags, unsigned* __restrict__ go,
    float* __restrict__ xbuf, float* __restrict__ partials)
{
    __shared__ float x_lds[N_];       // 16 KB: full state vector
    __shared__ float u_lds[D_];
    __shared__ float xnew_lds[RPB];
    const int tid = threadIdx.x;
    const int bid = blockIdx.x;
    const int wave = tid >> 6;        // 0..15
    const int lane = tid & 63;
    const int row0 = bid * RPB;

    for (int t = 0; t < T_; ++t) {
        // Reduce PREVIOUS step's y-partials (pipelined; blocks 0..63, wave 0).
        if (t > 0 && bid < O_ && wave == 0) {
            const float* p = partials + ((t - 1) & 1) * (O_ * NBLK) + bid * NBLK;
            float s = p[lane] + p[lane + 64] + p[lane + 128] + p[lane + 192];
            #pragma unroll
            for (int off = 32; off; off >>= 1) s += __shfl_xor(s, off);
            if (lane == 0) y[(t - 1) * O_ + bid] = s + bo[bid];
        }

        // Stage u_t and x_{t-1} into LDS.
        if (tid < D_) u_lds[tid] = inputs[t * D_ + tid];
        const float* xsrc = xbuf + ((t + 1) & 1) * N_;  // (t-1)&1 parity
        if (t == 0) {
            for (int i = tid; i < N_; i += NTHR) x_lds[i] = 0.f;
        } else {
            for (int i = tid; i < N_; i += NTHR) x_lds[i] = xsrc[i];
        }
        __syncthreads();

        // Dense matvec: one row per wave, float4 coalesced loads from W (L3).
        {
            const int row = row0 + wave;
            const float4* Wr = (const float4*)(W + (size_t)row * N_);
            const float4* xv = (const float4*)x_lds;
            float acc = 0.f;
            #pragma unroll 8
            for (int i = 0; i < N_ / 4 / 64; ++i) {   // 16 iterations
                float4 w4 = Wr[lane + 64 * i];
                float4 x4 = xv[lane + 64 * i];
                acc += w4.x * x4.x + w4.y * x4.y + w4.z * x4.z + w4.w * x4.w;
            }
            // Fold W_in @ u into the same reduction (D == 64 == wave size).
            acc += W_in[row * D_ + lane] * u_lds[lane];
            #pragma unroll
            for (int off = 32; off; off >>= 1) acc += __shfl_xor(acc, off);
            if (lane == 0) {
                float pre = acc + b[row];
                float xo = x_lds[row];  // zero at t==0 (LDS zeroed)
                float xn = (1.f - LEAK_) * xo + LEAK_ * tanhf(pre);
                xbuf[(t & 1) * N_ + row] = xn;
                xnew_lds[wave] = xn;
            }
        }
        __syncthreads();

        // Per-block partial of y_t = Wo @ x_new (64 outputs, 16 rows each).
        if (tid < O_) {
            float s = 0.f;
            #pragma unroll
            for (int r = 0; r < RPB; ++r)
                s += WoT[(row0 + r) * O_ + tid] * xnew_lds[r];
            partials[(t & 1) * (O_ * NBLK) + tid * NBLK + bid] = s;
        }

        grid_barrier(flags, go, (unsigned)(t + 1));
    }

    // Drain: reduce partials of the final step.
    if (bid < O_ && wave == 0) {
        const float* p = partials + ((T_ - 1) & 1) * (O_ * NBLK) + bid * NBLK;
        float s = p[lane] + p[lane + 64] + p[lane + 128] + p[lane + 192];
        #pragma unroll
        for (int off = 32; off; off >>= 1) s += __shfl_xor(s, off);
        if (lane == 0) y[(T_ - 1) * O_ + bid] = s + bo[bid];
    }
}

extern "C" void kernel_launch(void* const* d_in, const int* in_sizes, int n_in,
                              void* d_out, int out_size, void* d_ws, size_t ws_size,
                              hipStream_t stream) {
    const float* inputs = (const float*)d_in[0];
    const float* W      = (const float*)d_in[1];
    const float* W_in   = (const float*)d_in[2];
    const float* b      = (const float*)d_in[3];
    const float* W_out  = (const float*)d_in[4];
    float* y  = (float*)d_out;

    // Workspace layout:
    //   [0, 32 KB)      arrival flags, 128 B stride per block
    //   [32 KB, +64 B)  go word
    //   [64 KB, ...)    floats: xbuf[2*N] | partials[2*O*NBLK] | WoT[N*O] | bo[O]
    unsigned* flags = (unsigned*)d_ws;
    unsigned* go    = (unsigned*)((char*)d_ws + 32 * 1024);
    float* fws      = (float*)((char*)d_ws + 64 * 1024);
    float* xbuf     = fws;
    float* partials = xbuf + 2 * N_;
    float* WoT      = partials + 2 * O_ * NBLK;
    float* bo       = WoT + N_ * O_;

    // Reset barrier state every call (replay-deterministic).
    hipMemsetAsync(d_ws, 0, 64 * 1024, stream);

    hipLaunchKernelGGL(esn_prep, dim3((N_ * O_ + 255) / 256), dim3(256),
                       0, stream, W_out, WoT, bo);

    hipLaunchKernelGGL(esn_main, dim3(NBLK), dim3(NTHR), 0, stream,
                       inputs, W, W_in, b, WoT, bo, y, flags, go, xbuf, partials);
}

// Round 4
// 109939.990 us; speedup vs baseline: 1.7398x; 1.4721x over previous
//
#include <hip/hip_runtime.h>

constexpr int N_ = 4096;
constexpr int D_ = 64;
constexpr int O_ = 64;
constexpr int T_ = 4096;
constexpr float LEAK_ = 0.8f;
constexpr int NBLK = 256;   // blocks (1 per CU; all co-resident -> barrier safe)
constexpr int NTHR = 1024;  // 16 waves per block, 4 per SIMD
constexpr int RPB = N_ / NBLK;   // 16 rows per block, one row per wave
constexpr int KELL = 576;        // ELL slots/row (nnz ~410 +- 19; huge margin)
constexpr int SPL = KELL / 64;   // 9 slots per lane

// Prep A: transpose W_out weight part -> WoT[row][o], extract bias col bo.
__global__ void esn_prep(const float* __restrict__ W_out,
                         float* __restrict__ WoT, float* __restrict__ bo) {
    int idx = blockIdx.x * blockDim.x + threadIdx.x;
    if (idx < N_ * O_) {
        int row = idx / O_;
        int o = idx - row * O_;
        WoT[idx] = W_out[o * (N_ + 1) + row];
    }
    if (idx < O_) bo[idx] = W_out[idx * (N_ + 1) + N_];
}

// Prep B: dense W -> ELL (u16 cols + f32 vals, K slots/row, zero-padded).
// One wave per row; deterministic packing via ballot + prefix popcount.
__global__ __launch_bounds__(256) void esn_sparsify(
    const float* __restrict__ W,
    unsigned short* __restrict__ cols, float* __restrict__ vals) {
    const int wv = (blockIdx.x * 256 + threadIdx.x) >> 6;   // global wave = row
    const int lane = threadIdx.x & 63;
    if (wv >= N_) return;
    const float* Wr = W + (size_t)wv * N_;
    unsigned short* crow = cols + (size_t)wv * KELL;
    float* vrow = vals + (size_t)wv * KELL;
    const unsigned long long ltmask = (1ull << lane) - 1ull;
    int cnt = 0;
    for (int c0 = 0; c0 < N_; c0 += 64) {
        float w = Wr[c0 + lane];
        unsigned long long m = __ballot(w != 0.0f);
        if (w != 0.0f) {
            int pos = cnt + __popcll(m & ltmask);
            if (pos < KELL) { crow[pos] = (unsigned short)(c0 + lane); vrow[pos] = w; }
        }
        cnt += __popcll(m);           // wave-uniform
    }
    if (cnt > KELL) cnt = KELL;
    for (int p = cnt + lane; p < KELL; p += 64) { crow[p] = 0; vrow[p] = 0.0f; }
}

__device__ __forceinline__ unsigned ld_acq(const unsigned* p) {
    return __hip_atomic_load(p, __ATOMIC_ACQUIRE, __HIP_MEMORY_SCOPE_AGENT);
}
__device__ __forceinline__ void st_rel(unsigned* p, unsigned v) {
    __hip_atomic_store(p, v, __ATOMIC_RELEASE, __HIP_MEMORY_SCOPE_AGENT);
}

// Flag-tree grid barrier: per-block padded arrival flags (no RMW contention),
// block 0 gathers and publishes `go`. All blocks co-resident -> no deadlock.
__device__ __forceinline__ void grid_barrier(unsigned* flags, unsigned* go,
                                             unsigned tgt) {
    __syncthreads();
    if (blockIdx.x == 0) {
        if (threadIdx.x < NBLK) {
            if (threadIdx.x == 0) st_rel(&flags[0], tgt);
            while (ld_acq(&flags[threadIdx.x * 32]) < tgt)
                __builtin_amdgcn_s_sleep(2);
        }
        __syncthreads();
        if (threadIdx.x == 0) st_rel(go, tgt);
    } else {
        if (threadIdx.x == 0) {
            st_rel(&flags[blockIdx.x * 32], tgt);
            while (ld_acq(go) < tgt) __builtin_amdgcn_s_sleep(2);
        }
        __syncthreads();
    }
}

__global__ __launch_bounds__(NTHR) void esn_main(
    const float* __restrict__ inputs,
    const unsigned short* __restrict__ cols, const float* __restrict__ vals,
    const float* __restrict__ W_in, const float* __restrict__ b,
    const float* __restrict__ WoT, const float* __restrict__ bo,
    float* __restrict__ y, unsigned* __restrict__ flags, unsigned* __restrict__ go,
    float* __restrict__ xbuf, float* __restrict__ partials)
{
    __shared__ float x_lds[N_];       // 16 KB: full state vector
    __shared__ float u_lds[D_];
    __shared__ float xnew_lds[RPB];
    const int tid = threadIdx.x;
    const int bid = blockIdx.x;
    const int wave = tid >> 6;        // 0..15
    const int lane = tid & 63;
    const int row0 = bid * RPB;
    const int row = row0 + wave;      // this wave's reservoir row

    for (int t = 0; t < T_; ++t) {
        // Reduce PREVIOUS step's y-partials (pipelined; blocks 0..63, wave 0).
        if (t > 0 && bid < O_ && wave == 0) {
            const float* p = partials + ((t - 1) & 1) * (O_ * NBLK);
            float s = p[lane * O_ + bid] + p[(lane + 64) * O_ + bid]
                    + p[(lane + 128) * O_ + bid] + p[(lane + 192) * O_ + bid];
            #pragma unroll
            for (int off = 32; off; off >>= 1) s += __shfl_xor(s, off);
            if (lane == 0) y[(t - 1) * O_ + bid] = s + bo[bid];
        }

        // Stage u_t and x_{t-1} into LDS (one float4 per thread).
        if (tid < D_) u_lds[tid] = inputs[t * D_ + tid];
        if (t == 0) {
            ((float4*)x_lds)[tid] = make_float4(0.f, 0.f, 0.f, 0.f);
        } else {
            const float4* xsrc = (const float4*)(xbuf + ((t + 1) & 1) * N_);
            ((float4*)x_lds)[tid] = xsrc[tid];
        }
        __syncthreads();

        // Sparse ELL matvec: one row per wave, 9 gather-MACs per lane.
        {
            const unsigned short* crow = cols + (size_t)row * KELL;
            const float* vrow = vals + (size_t)row * KELL;
            float acc = 0.f;
            #pragma unroll
            for (int j = 0; j < SPL; ++j) {
                int c = crow[64 * j + lane];
                float v = vrow[64 * j + lane];
                acc += v * x_lds[c];
            }
            // Fold W_in @ u into the same reduction (D == 64 == wave size).
            acc += W_in[row * D_ + lane] * u_lds[lane];
            #pragma unroll
            for (int off = 32; off; off >>= 1) acc += __shfl_xor(acc, off);
            if (lane == 0) {
                float pre = acc + b[row];
                float xo = x_lds[row];  // zero at t==0
                float xn = (1.f - LEAK_) * xo + LEAK_ * tanhf(pre);
                xbuf[(t & 1) * N_ + row] = xn;
                xnew_lds[wave] = xn;
            }
        }
        __syncthreads();

        // Per-block partial of y_t = Wo @ x_new (contiguous 256 B write).
        if (tid < O_) {
            float s = 0.f;
            #pragma unroll
            for (int r = 0; r < RPB; ++r)
                s += WoT[(row0 + r) * O_ + tid] * xnew_lds[r];
            partials[(t & 1) * (O_ * NBLK) + bid * O_ + tid] = s;
        }

        grid_barrier(flags, go, (unsigned)(t + 1));
    }

    // Drain: reduce partials of the final step.
    if (bid < O_ && wave == 0) {
        const float* p = partials + ((T_ - 1) & 1) * (O_ * NBLK);
        float s = p[lane * O_ + bid] + p[(lane + 64) * O_ + bid]
                + p[(lane + 128) * O_ + bid] + p[(lane + 192) * O_ + bid];
        #pragma unroll
        for (int off = 32; off; off >>= 1) s += __shfl_xor(s, off);
        if (lane == 0) y[(T_ - 1) * O_ + bid] = s + bo[bid];
    }
}

extern "C" void kernel_launch(void* const* d_in, const int* in_sizes, int n_in,
                              void* d_out, int out_size, void* d_ws, size_t ws_size,
                              hipStream_t stream) {
    const float* inputs = (const float*)d_in[0];
    const float* W      = (const float*)d_in[1];
    const float* W_in   = (const float*)d_in[2];
    const float* b      = (const float*)d_in[3];
    const float* W_out  = (const float*)d_in[4];
    float* y  = (float*)d_out;

    // Workspace layout:
    //   [0, 32 KB)        arrival flags, 128 B stride per block
    //   [32 KB, +64 B)    go word
    //   [64 KB ...)       floats: xbuf[2N] | partials[2*NBLK*O] | WoT[N*O] | bo[O]
    //                     | vals[N*KELL] ; then u16 cols[N*KELL]
    unsigned* flags = (unsigned*)d_ws;
    unsigned* go    = (unsigned*)((char*)d_ws + 32 * 1024);
    float* fws      = (float*)((char*)d_ws + 64 * 1024);
    float* xbuf     = fws;
    float* partials = xbuf + 2 * N_;
    float* WoT      = partials + 2 * NBLK * O_;
    float* bo       = WoT + N_ * O_;
    float* vals     = bo + O_;
    unsigned short* cols = (unsigned short*)(vals + (size_t)N_ * KELL);

    // Reset barrier state every call (replay-deterministic).
    hipMemsetAsync(d_ws, 0, 64 * 1024, stream);

    hipLaunchKernelGGL(esn_prep, dim3((N_ * O_ + 255) / 256), dim3(256),
                       0, stream, W_out, WoT, bo);
    hipLaunchKernelGGL(esn_sparsify, dim3(N_ * 64 / 256), dim3(256),
                       0, stream, W, cols, vals);

    hipLaunchKernelGGL(esn_main, dim3(NBLK), dim3(NTHR), 0, stream,
                       inputs, cols, vals, W_in, b, WoT, bo, y,
                       flags, go, xbuf, partials);
}

// Round 5
// 30441.135 us; speedup vs baseline: 6.2833x; 3.6116x over previous
//
#include <hip/hip_runtime.h>

constexpr int N_ = 4096;
constexpr int D_ = 64;
constexpr int O_ = 64;
constexpr int T_ = 4096;
constexpr float LEAK_ = 0.8f;
constexpr int NBLK = 64;    // blocks (≤ CU count; all co-resident -> barrier safe)
constexpr int NTHR = 1024;  // 16 waves per block
constexpr int RPB = N_ / NBLK;   // 64 rows per block
constexpr int RPW = RPB / 16;    // 4 rows per wave
constexpr int KELL = 576;        // ELL slots/row (nnz ~410 +- 19; huge margin)
constexpr int SPL = KELL / 64;   // 9 slots per lane

// Prep A: transpose W_out weight part -> WoT[row][o], extract bias col bo.
__global__ void esn_prep(const float* __restrict__ W_out,
                         float* __restrict__ WoT, float* __restrict__ bo) {
    int idx = blockIdx.x * blockDim.x + threadIdx.x;
    if (idx < N_ * O_) {
        int row = idx / O_;
        int o = idx - row * O_;
        WoT[idx] = W_out[o * (N_ + 1) + row];
    }
    if (idx < O_) bo[idx] = W_out[idx * (N_ + 1) + N_];
}

// Prep B: dense W -> ELL (u16 cols + f32 vals, K slots/row, zero-padded).
__global__ __launch_bounds__(256) void esn_sparsify(
    const float* __restrict__ W,
    unsigned short* __restrict__ cols, float* __restrict__ vals) {
    const int wv = (blockIdx.x * 256 + threadIdx.x) >> 6;   // global wave = row
    const int lane = threadIdx.x & 63;
    if (wv >= N_) return;
    const float* Wr = W + (size_t)wv * N_;
    unsigned short* crow = cols + (size_t)wv * KELL;
    float* vrow = vals + (size_t)wv * KELL;
    const unsigned long long ltmask = (1ull << lane) - 1ull;
    int cnt = 0;
    for (int c0 = 0; c0 < N_; c0 += 64) {
        float w = Wr[c0 + lane];
        unsigned long long m = __ballot(w != 0.0f);
        if (w != 0.0f) {
            int pos = cnt + __popcll(m & ltmask);
            if (pos < KELL) { crow[pos] = (unsigned short)(c0 + lane); vrow[pos] = w; }
        }
        cnt += __popcll(m);           // wave-uniform
    }
    if (cnt > KELL) cnt = KELL;
    for (int p = cnt + lane; p < KELL; p += 64) { crow[p] = 0; vrow[p] = 0.0f; }
}

__device__ __forceinline__ unsigned ld_acq(const unsigned* p) {
    return __hip_atomic_load(p, __ATOMIC_ACQUIRE, __HIP_MEMORY_SCOPE_AGENT);
}
__device__ __forceinline__ void st_rel(unsigned* p, unsigned v) {
    __hip_atomic_store(p, v, __ATOMIC_RELEASE, __HIP_MEMORY_SCOPE_AGENT);
}

__global__ __launch_bounds__(NTHR) void esn_main(
    const float* __restrict__ inputs,
    const unsigned short* __restrict__ cols, const float* __restrict__ vals,
    const float* __restrict__ W_in, const float* __restrict__ b,
    const float* __restrict__ WoT, const float* __restrict__ bo,
    float* __restrict__ y, unsigned* __restrict__ flags,
    float* __restrict__ xbuf, float* __restrict__ partials)
{
    __shared__ float x_lds[N_];       // 16 KB: full state vector
    __shared__ float u_lds[D_];
    __shared__ float xnew_lds[RPB];
    const int tid = threadIdx.x;
    const int bid = blockIdx.x;
    const int wave = tid >> 6;        // 0..15
    const int lane = tid & 63;
    const int row0 = bid * RPB;

    for (int t = 0; t < T_; ++t) {
        // Stage u_t and x_{t-1} into LDS (one float4 per thread).
        if (tid < D_) u_lds[tid] = inputs[t * D_ + tid];
        if (t == 0) {
            ((float4*)x_lds)[tid] = make_float4(0.f, 0.f, 0.f, 0.f);
        } else {
            const float4* xsrc = (const float4*)(xbuf + ((t + 1) & 1) * N_);
            ((float4*)x_lds)[tid] = xsrc[tid];
        }
        __syncthreads();

        // Sparse ELL matvec: 4 rows per wave, 9 gather-MACs/lane/row.
        #pragma unroll
        for (int r = 0; r < RPW; ++r) {
            const int row = row0 + wave * RPW + r;
            const unsigned short* crow = cols + (size_t)row * KELL;
            const float* vrow = vals + (size_t)row * KELL;
            float acc = 0.f;
            #pragma unroll
            for (int j = 0; j < SPL; ++j) {
                int c = crow[64 * j + lane];
                float v = vrow[64 * j + lane];
                acc += v * x_lds[c];
            }
            // Fold W_in @ u into the same reduction (D == 64 == wave size).
            acc += W_in[row * D_ + lane] * u_lds[lane];
            #pragma unroll
            for (int off = 32; off; off >>= 1) acc += __shfl_xor(acc, off);
            if (lane == 0) {
                float pre = acc + b[row];
                float xo = x_lds[row];  // zero at t==0
                float xn = (1.f - LEAK_) * xo + LEAK_ * tanhf(pre);
                xbuf[(t & 1) * N_ + row] = xn;
                xnew_lds[wave * RPW + r] = xn;
            }
        }
        __syncthreads();

        // Per-block partial of y_t = Wo @ x_new (contiguous 256 B write).
        if (tid < O_) {
            float s = 0.f;
            #pragma unroll 8
            for (int r = 0; r < RPB; ++r)
                s += WoT[(row0 + r) * O_ + tid] * xnew_lds[r];
            partials[(t & 1) * (NBLK * O_) + bid * O_ + tid] = s;
        }
        __syncthreads();   // x + partial writes complete before publish

        // Publish arrival, hide y-reduction of step t-1 in the wait window,
        // then poll ALL 64 flags directly (one lane per flag, single trip).
        if (tid == 0) st_rel(&flags[bid * 16], (unsigned)(t + 1));
        if (wave == 0) {
            if (t > 0) {
                const float* p = partials + ((t - 1) & 1) * (NBLK * O_);
                float s = p[lane * O_ + bid];   // gather across 64 blocks
                #pragma unroll
                for (int off = 32; off; off >>= 1) s += __shfl_xor(s, off);
                if (lane == 0) y[(t - 1) * O_ + bid] = s + bo[bid];
            }
            while (__ballot(ld_acq(&flags[lane * 16]) < (unsigned)(t + 1)) != 0ull) {}
        }
        __syncthreads();
    }

    // Drain: y for the final step (flags==T already acquired by all blocks).
    if (wave == 0) {
        const float* p = partials + ((T_ - 1) & 1) * (NBLK * O_);
        float s = p[lane * O_ + bid];
        #pragma unroll
        for (int off = 32; off; off >>= 1) s += __shfl_xor(s, off);
        if (lane == 0) y[(T_ - 1) * O_ + bid] = s + bo[bid];
    }
}

extern "C" void kernel_launch(void* const* d_in, const int* in_sizes, int n_in,
                              void* d_out, int out_size, void* d_ws, size_t ws_size,
                              hipStream_t stream) {
    const float* inputs = (const float*)d_in[0];
    const float* W      = (const float*)d_in[1];
    const float* W_in   = (const float*)d_in[2];
    const float* b      = (const float*)d_in[3];
    const float* W_out  = (const float*)d_in[4];
    float* y  = (float*)d_out;

    // Workspace layout:
    //   [0, 64 KB)   arrival flags (64 x 64 B stride) + padding, zeroed per call
    //   [64 KB ...)  floats: xbuf[2N] | partials[2*NBLK*O] | WoT[N*O] | bo[O]
    //                | vals[N*KELL] ; then u16 cols[N*KELL]
    unsigned* flags = (unsigned*)d_ws;
    float* fws      = (float*)((char*)d_ws + 64 * 1024);
    float* xbuf     = fws;
    float* partials = xbuf + 2 * N_;
    float* WoT      = partials + 2 * NBLK * O_;
    float* bo       = WoT + N_ * O_;
    float* vals     = bo + O_;
    unsigned short* cols = (unsigned short*)(vals + (size_t)N_ * KELL);

    // Reset barrier state every call (replay-deterministic).
    hipMemsetAsync(d_ws, 0, 64 * 1024, stream);

    hipLaunchKernelGGL(esn_prep, dim3((N_ * O_ + 255) / 256), dim3(256),
                       0, stream, W_out, WoT, bo);
    hipLaunchKernelGGL(esn_sparsify, dim3(N_ * 64 / 256), dim3(256),
                       0, stream, W, cols, vals);

    hipLaunchKernelGGL(esn_main, dim3(NBLK), dim3(NTHR), 0, stream,
                       inputs, cols, vals, W_in, b, WoT, bo, y,
                       flags, xbuf, partials);
}

// Round 6
// 28437.357 us; speedup vs baseline: 6.7260x; 1.0705x over previous
//
#include <hip/hip_runtime.h>

constexpr int N_ = 4096;
constexpr int D_ = 64;
constexpr int O_ = 64;
constexpr int T_ = 4096;
constexpr float LEAK_ = 0.8f;
constexpr int NBLK = 128;        // blocks (<=256 CUs; all co-resident)
constexpr int NTHR = 1024;       // 16 waves per block
constexpr int NWAVE = NTHR / 64; // 16
constexpr int RPB = N_ / NBLK;   // 32 rows per block
constexpr int RPW = RPB / NWAVE; // 2 rows per wave
constexpr int KELL = 576;        // ELL slots/row (9 groups of 64)
constexpr int GRP = KELL / 64;   // 9
constexpr int PDEPTH = 4;        // partials ring depth (y lags 2 steps)

// Prep A: transpose W_out weight part -> WoT[row][o], extract bias col bo.
__global__ void esn_prep(const float* __restrict__ W_out,
                         float* __restrict__ WoT, float* __restrict__ bo) {
    int idx = blockIdx.x * blockDim.x + threadIdx.x;
    if (idx < N_ * O_) {
        int row = idx / O_;
        int o = idx - row * O_;
        WoT[idx] = W_out[o * (N_ + 1) + row];
    }
    if (idx < O_) bo[idx] = W_out[idx * (N_ + 1) + N_];
}

// Prep B: dense W -> ELL with BANK-BALANCED slot assignment.
// One 64-thread block per row. Each nnz's LDS bank is (col & 31); we
// round-robin each bank's entries across the 9 slot-groups so a group's 64
// columns hit each bank <=~2-3 times (2-way LDS conflict is free).
__global__ __launch_bounds__(64) void esn_sparsify(
    const float* __restrict__ W,
    unsigned short* __restrict__ cols, float* __restrict__ vals) {
    const int row = blockIdx.x;
    const int lane = threadIdx.x;
    __shared__ unsigned short nnz_c[512];
    __shared__ float nnz_w[512];
    __shared__ short slot_nnz[KELL];
    for (int s = lane; s < KELL; s += 64) slot_nnz[s] = -1;

    const float* Wr = W + (size_t)row * N_;
    const unsigned long long ltmask = (1ull << lane) - 1ull;
    int cnt = 0;
    for (int c0 = 0; c0 < N_; c0 += 64) {
        float w = Wr[c0 + lane];
        unsigned long long m = __ballot(w != 0.0f);
        if (w != 0.0f) {
            int pos = cnt + __popcll(m & ltmask);
            if (pos < 512) { nnz_c[pos] = (unsigned short)(c0 + lane); nnz_w[pos] = w; }
        }
        cnt += __popcll(m);
    }
    if (cnt > 512) cnt = 512;
    __syncthreads();

    if (lane == 0) {
        unsigned char fill[GRP];
        unsigned char nxt[32];
        for (int g = 0; g < GRP; ++g) fill[g] = 0;
        for (int bnk = 0; bnk < 32; ++bnk) nxt[bnk] = 0;
        for (int i = 0; i < cnt; ++i) {
            int bnk = nnz_c[i] & 31;
            int g = nxt[bnk];
            int tries = 0;
            while (fill[g] >= 64 && tries < GRP) { g = (g + 1) % GRP; ++tries; }
            slot_nnz[g * 64 + fill[g]] = (short)i;
            fill[g]++;
            nxt[bnk] = (unsigned char)((g + 1) % GRP);
        }
    }
    __syncthreads();

    unsigned short* crow = cols + (size_t)row * KELL;
    float* vrow = vals + (size_t)row * KELL;
    for (int s = lane; s < KELL; s += 64) {
        int i = slot_nnz[s];
        crow[s] = (i >= 0) ? nnz_c[i] : 0;
        vrow[s] = (i >= 0) ? nnz_w[i] : 0.0f;
    }
}

__device__ __forceinline__ unsigned ld_acq(const unsigned* p) {
    return __hip_atomic_load(p, __ATOMIC_ACQUIRE, __HIP_MEMORY_SCOPE_AGENT);
}
__device__ __forceinline__ void st_rel(unsigned* p, unsigned v) {
    __hip_atomic_store(p, v, __ATOMIC_RELEASE, __HIP_MEMORY_SCOPE_AGENT);
}

__global__ __launch_bounds__(NTHR) void esn_main(
    const float* __restrict__ inputs,
    const unsigned short* __restrict__ cols, const float* __restrict__ vals,
    const float* __restrict__ W_in, const float* __restrict__ b,
    const float* __restrict__ WoT, const float* __restrict__ bo,
    float* __restrict__ y, unsigned* __restrict__ flags,
    float* __restrict__ xbuf, float* __restrict__ partials)
{
    __shared__ float x_lds[N_];          // 16 KB
    __shared__ float u_lds[D_];
    __shared__ float xnew_lds[RPB];
    __shared__ float pw_lds[NWAVE][O_];  // 4 KB
    const int tid = threadIdx.x;
    const int bid = blockIdx.x;
    const int wave = tid >> 6;
    const int lane = tid & 63;
    const int row0 = bid * RPB;

    for (int t = 0; t < T_; ++t) {
        // Stage u_t and x_{t-1} into LDS (one float4 per thread).
        if (tid < D_) u_lds[tid] = inputs[t * D_ + tid];
        if (t == 0) {
            ((float4*)x_lds)[tid] = make_float4(0.f, 0.f, 0.f, 0.f);
        } else {
            const float4* xsrc = (const float4*)(xbuf + ((t + 1) & 1) * N_);
            ((float4*)x_lds)[tid] = xsrc[tid];
        }
        __syncthreads();

        // Sparse ELL matvec: 2 rows per wave; prefetch cols/vals, then gathers.
        float xn_r[RPW];
        #pragma unroll
        for (int r = 0; r < RPW; ++r) {
            const int row = row0 + wave * RPW + r;
            const unsigned short* crow = cols + (size_t)row * KELL;
            const float* vrow = vals + (size_t)row * KELL;
            unsigned short cc[GRP];
            float vv[GRP];
            #pragma unroll
            for (int j = 0; j < GRP; ++j) {
                cc[j] = crow[64 * j + lane];
                vv[j] = vrow[64 * j + lane];
            }
            float acc = 0.f;
            #pragma unroll
            for (int j = 0; j < GRP; ++j) acc += vv[j] * x_lds[cc[j]];
            acc += W_in[row * D_ + lane] * u_lds[lane];   // fold W_in @ u
            #pragma unroll
            for (int off = 32; off; off >>= 1) acc += __shfl_xor(acc, off);
            // butterfly -> every lane holds the full row sum
            float pre = acc + b[row];
            float xo = x_lds[row];
            float xn = (1.f - LEAK_) * xo + LEAK_ * tanhf(pre);
            xn_r[r] = xn;
            if (lane == 0) xnew_lds[wave * RPW + r] = xn;
        }
        __syncthreads();

        // Wave 0: coalesced x-store + EARLY flag publish (x is the only
        // cross-block dependency; readout partials ride the next release).
        if (wave == 0) {
            if (lane < RPB) xbuf[(t & 1) * N_ + row0 + lane] = xnew_lds[lane];
            if (lane == 0) st_rel(&flags[bid * 16], (unsigned)(t + 1));
        }

        // All waves: readout partial for own 2 rows (coalesced WoT loads).
        float pw = 0.f;
        #pragma unroll
        for (int r = 0; r < RPW; ++r)
            pw += WoT[(row0 + wave * RPW + r) * O_ + lane] * xn_r[r];
        pw_lds[wave][lane] = pw;
        __syncthreads();

        // Wave 0: block partial -> global ring; then poll.  Wave 1: y(t-2)
        // reduction concurrently (ordered via release(t)/acquire(t) chain).
        if (wave == 0) {
            float s = 0.f;
            #pragma unroll
            for (int w = 0; w < NWAVE; ++w) s += pw_lds[w][lane];
            partials[(t & (PDEPTH - 1)) * (NBLK * O_) + bid * O_ + lane] = s;
            const unsigned tgt = (unsigned)(t + 1);
            while (true) {
                unsigned f0 = ld_acq(&flags[lane * 16]);
                unsigned f1 = ld_acq(&flags[(lane + 64) * 16]);
                if (__ballot((f0 < tgt) || (f1 < tgt)) == 0ull) break;
            }
        } else if (wave == 1 && t >= 2 && bid < O_) {
            const float* p = partials + ((t - 2) & (PDEPTH - 1)) * (NBLK * O_);
            float s = p[lane * O_ + bid] + p[(lane + 64) * O_ + bid];
            #pragma unroll
            for (int off = 32; off; off >>= 1) s += __shfl_xor(s, off);
            if (lane == 0) y[(t - 2) * O_ + bid] = s + bo[bid];
        }
        __syncthreads();
    }

    // Drain: one extra mini-barrier so partial(T-1) is release-ordered, then
    // reduce y(T-2) and y(T-1).
    if (tid == 0) st_rel(&flags[bid * 16], (unsigned)(T_ + 1));
    if (wave == 0) {
        const unsigned tgt = (unsigned)(T_ + 1);
        while (true) {
            unsigned f0 = ld_acq(&flags[lane * 16]);
            unsigned f1 = ld_acq(&flags[(lane + 64) * 16]);
            if (__ballot((f0 < tgt) || (f1 < tgt)) == 0ull) break;
        }
    }
    __syncthreads();
    if (bid < O_ && wave < 2) {
        const int tt = T_ - 2 + wave;   // wave0 -> T-2, wave1 -> T-1
        const float* p = partials + (tt & (PDEPTH - 1)) * (NBLK * O_);
        float s = p[lane * O_ + bid] + p[(lane + 64) * O_ + bid];
        #pragma unroll
        for (int off = 32; off; off >>= 1) s += __shfl_xor(s, off);
        if (lane == 0) y[tt * O_ + bid] = s + bo[bid];
    }
}

extern "C" void kernel_launch(void* const* d_in, const int* in_sizes, int n_in,
                              void* d_out, int out_size, void* d_ws, size_t ws_size,
                              hipStream_t stream) {
    const float* inputs = (const float*)d_in[0];
    const float* W      = (const float*)d_in[1];
    const float* W_in   = (const float*)d_in[2];
    const float* b      = (const float*)d_in[3];
    const float* W_out  = (const float*)d_in[4];
    float* y  = (float*)d_out;

    // Workspace:
    //   [0, 64 KB)   arrival flags (NBLK x 64 B stride), zeroed per call
    //   [64 KB ...)  floats: xbuf[2N] | partials[PDEPTH*NBLK*O] | WoT[N*O]
    //                | bo[O] | vals[N*KELL] ; then u16 cols[N*KELL]
    unsigned* flags = (unsigned*)d_ws;
    float* fws      = (float*)((char*)d_ws + 64 * 1024);
    float* xbuf     = fws;
    float* partials = xbuf + 2 * N_;
    float* WoT      = partials + PDEPTH * NBLK * O_;
    float* bo       = WoT + N_ * O_;
    float* vals     = bo + O_;
    unsigned short* cols = (unsigned short*)(vals + (size_t)N_ * KELL);

    hipMemsetAsync(d_ws, 0, 64 * 1024, stream);   // reset barrier state

    hipLaunchKernelGGL(esn_prep, dim3((N_ * O_ + 255) / 256), dim3(256),
                       0, stream, W_out, WoT, bo);
    hipLaunchKernelGGL(esn_sparsify, dim3(N_), dim3(64),
                       0, stream, W, cols, vals);

    hipLaunchKernelGGL(esn_main, dim3(NBLK), dim3(NTHR), 0, stream,
                       inputs, cols, vals, W_in, b, WoT, bo, y,
                       flags, xbuf, partials);
}

// Round 7
// 16766.959 us; speedup vs baseline: 11.4075x; 1.6960x over previous
//
#include <hip/hip_runtime.h>

constexpr int N_ = 4096;
constexpr int D_ = 64;
constexpr int O_ = 64;
constexpr int T_ = 4096;
constexpr float LEAK_ = 0.8f;
constexpr int NBLK = 128;        // blocks (<=256 CUs; all co-resident)
constexpr int NTHR = 1024;       // 16 waves per block
constexpr int NWAVE = NTHR / 64; // 16
constexpr int RPB = N_ / NBLK;   // 32 rows per block
constexpr int RPW = RPB / NWAVE; // 2 rows per wave
constexpr int KELL = 576;        // ELL slots/row (9 groups of 64)
constexpr int GRP = KELL / 64;   // 9
constexpr int PDEPTH = 4;        // partials ring depth (y lags 2 steps)

#define LD_RLX(p) __hip_atomic_load((p), __ATOMIC_RELAXED, __HIP_MEMORY_SCOPE_AGENT)
#define ST_RLX(p, v) __hip_atomic_store((p), (v), __ATOMIC_RELAXED, __HIP_MEMORY_SCOPE_AGENT)

// Prep A: transpose W_out weight part -> WoT[row][o], extract bias col bo.
__global__ void esn_prep(const float* __restrict__ W_out,
                         float* __restrict__ WoT, float* __restrict__ bo) {
    int idx = blockIdx.x * blockDim.x + threadIdx.x;
    if (idx < N_ * O_) {
        int row = idx / O_;
        int o = idx - row * O_;
        WoT[idx] = W_out[o * (N_ + 1) + row];
    }
    if (idx < O_) bo[idx] = W_out[idx * (N_ + 1) + N_];
}

// Prep B: dense W -> ELL with BANK-BALANCED slot assignment (bank = col & 31,
// round-robined across the 9 slot-groups so per-group conflicts are ~2-3 way).
__global__ __launch_bounds__(64) void esn_sparsify(
    const float* __restrict__ W,
    unsigned short* __restrict__ cols, float* __restrict__ vals) {
    const int row = blockIdx.x;
    const int lane = threadIdx.x;
    __shared__ unsigned short nnz_c[512];
    __shared__ float nnz_w[512];
    __shared__ short slot_nnz[KELL];
    for (int s = lane; s < KELL; s += 64) slot_nnz[s] = -1;

    const float* Wr = W + (size_t)row * N_;
    const unsigned long long ltmask = (1ull << lane) - 1ull;
    int cnt = 0;
    for (int c0 = 0; c0 < N_; c0 += 64) {
        float w = Wr[c0 + lane];
        unsigned long long m = __ballot(w != 0.0f);
        if (w != 0.0f) {
            int pos = cnt + __popcll(m & ltmask);
            if (pos < 512) { nnz_c[pos] = (unsigned short)(c0 + lane); nnz_w[pos] = w; }
        }
        cnt += __popcll(m);
    }
    if (cnt > 512) cnt = 512;
    __syncthreads();

    if (lane == 0) {
        unsigned char fill[GRP];
        unsigned char nxt[32];
        for (int g = 0; g < GRP; ++g) fill[g] = 0;
        for (int bnk = 0; bnk < 32; ++bnk) nxt[bnk] = 0;
        for (int i = 0; i < cnt; ++i) {
            int bnk = nnz_c[i] & 31;
            int g = nxt[bnk];
            int tries = 0;
            while (fill[g] >= 64 && tries < GRP) { g = (g + 1) % GRP; ++tries; }
            slot_nnz[g * 64 + fill[g]] = (short)i;
            fill[g]++;
            nxt[bnk] = (unsigned char)((g + 1) % GRP);
        }
    }
    __syncthreads();

    unsigned short* crow = cols + (size_t)row * KELL;
    float* vrow = vals + (size_t)row * KELL;
    for (int s = lane; s < KELL; s += 64) {
        int i = slot_nnz[s];
        crow[s] = (i >= 0) ? nnz_c[i] : 0;
        vrow[s] = (i >= 0) ? nnz_w[i] : 0.0f;
    }
}

__global__ __launch_bounds__(NTHR) void esn_main(
    const float* __restrict__ inputs,
    const unsigned short* __restrict__ cols, const float* __restrict__ vals,
    const float* __restrict__ W_in, const float* __restrict__ b,
    const float* __restrict__ WoT, const float* __restrict__ bo,
    float* __restrict__ y, unsigned* __restrict__ flags,
    float* __restrict__ xbuf, float* __restrict__ partials)
{
    __shared__ float x_lds[N_];          // 16 KB
    __shared__ float u_lds[D_];
    __shared__ float xnew_lds[RPB];
    __shared__ float pw_lds[NWAVE][O_];  // 4 KB
    const int tid = threadIdx.x;
    const int bid = blockIdx.x;
    const int wave = tid >> 6;
    const int lane = tid & 63;
    const int row0 = bid * RPB;

    for (int t = 0; t < T_; ++t) {
        // Stage u_t and x_{t-1} into LDS. x comes through MALL-coherent
        // relaxed atomic loads (no cache-maintenance instructions).
        if (tid < D_) u_lds[tid] = inputs[t * D_ + tid];
        if (t == 0) {
            ((float4*)x_lds)[tid] = make_float4(0.f, 0.f, 0.f, 0.f);
        } else {
            const float* xsrc = xbuf + ((t + 1) & 1) * N_ + tid * 4;
            float a0 = LD_RLX(xsrc + 0);
            float a1 = LD_RLX(xsrc + 1);
            float a2 = LD_RLX(xsrc + 2);
            float a3 = LD_RLX(xsrc + 3);
            ((float4*)x_lds)[tid] = make_float4(a0, a1, a2, a3);
        }
        __syncthreads();

        // Sparse ELL matvec: 2 rows per wave; prefetch cols/vals, then gathers.
        float xn_r[RPW];
        #pragma unroll
        for (int r = 0; r < RPW; ++r) {
            const int row = row0 + wave * RPW + r;
            const unsigned short* crow = cols + (size_t)row * KELL;
            const float* vrow = vals + (size_t)row * KELL;
            unsigned short cc[GRP];
            float vv[GRP];
            #pragma unroll
            for (int j = 0; j < GRP; ++j) {
                cc[j] = crow[64 * j + lane];
                vv[j] = vrow[64 * j + lane];
            }
            float acc = 0.f;
            #pragma unroll
            for (int j = 0; j < GRP; ++j) acc += vv[j] * x_lds[cc[j]];
            acc += W_in[row * D_ + lane] * u_lds[lane];   // fold W_in @ u
            #pragma unroll
            for (int off = 32; off; off >>= 1) acc += __shfl_xor(acc, off);
            // butterfly -> every lane holds the full row sum
            float pre = acc + b[row];
            float xo = x_lds[row];
            float xn = (1.f - LEAK_) * xo + LEAK_ * tanhf(pre);
            xn_r[r] = xn;
            if (lane == 0) xnew_lds[wave * RPW + r] = xn;
        }
        __syncthreads();

        // Wave 0: x-store (relaxed, MALL write-through), wait store completion,
        // then publish flag (relaxed). Hand-rolled release: vmcnt(0) orders the
        // x stores (and last step's partial store) before the flag.
        if (wave == 0) {
            if (lane < RPB)
                ST_RLX(&xbuf[(t & 1) * N_ + row0 + lane], xnew_lds[lane]);
            asm volatile("s_waitcnt vmcnt(0)" ::: "memory");
            if (lane == 0) ST_RLX(&flags[bid * 16], (unsigned)(t + 1));
        }

        // All waves: readout partial for own 2 rows (coalesced WoT loads).
        float pw = 0.f;
        #pragma unroll
        for (int r = 0; r < RPW; ++r)
            pw += WoT[(row0 + wave * RPW + r) * O_ + lane] * xn_r[r];
        pw_lds[wave][lane] = pw;
        __syncthreads();

        // Wave 0: block partial -> global ring; then poll (relaxed loads, no
        // buffer_inv).  Wave 1: y(t-2) reduction concurrently.
        if (wave == 0) {
            float s = 0.f;
            #pragma unroll
            for (int w = 0; w < NWAVE; ++w) s += pw_lds[w][lane];
            ST_RLX(&partials[(t & (PDEPTH - 1)) * (NBLK * O_) + bid * O_ + lane], s);
            const unsigned tgt = (unsigned)(t + 1);
            while (true) {
                unsigned f0 = LD_RLX(&flags[lane * 16]);
                unsigned f1 = LD_RLX(&flags[(lane + 64) * 16]);
                if (__ballot((f0 < tgt) || (f1 < tgt)) == 0ull) break;
            }
            asm volatile("" ::: "memory");   // compiler barrier: no hoisting past poll
        } else if (wave == 1 && t >= 2 && bid < O_) {
            const float* p = partials + ((t - 2) & (PDEPTH - 1)) * (NBLK * O_);
            float s = LD_RLX(&p[lane * O_ + bid]) + LD_RLX(&p[(lane + 64) * O_ + bid]);
            #pragma unroll
            for (int off = 32; off; off >>= 1) s += __shfl_xor(s, off);
            if (lane == 0) y[(t - 2) * O_ + bid] = s + bo[bid];
        }
        __syncthreads();
    }

    // Drain: one extra mini-barrier so partial(T-1) is ordered, then y(T-2/T-1).
    if (tid == 0) {
        asm volatile("s_waitcnt vmcnt(0)" ::: "memory");
        ST_RLX(&flags[bid * 16], (unsigned)(T_ + 1));
    }
    if (wave == 0) {
        const unsigned tgt = (unsigned)(T_ + 1);
        while (true) {
            unsigned f0 = LD_RLX(&flags[lane * 16]);
            unsigned f1 = LD_RLX(&flags[(lane + 64) * 16]);
            if (__ballot((f0 < tgt) || (f1 < tgt)) == 0ull) break;
        }
        asm volatile("" ::: "memory");
    }
    __syncthreads();
    if (bid < O_ && wave < 2) {
        const int tt = T_ - 2 + wave;   // wave0 -> T-2, wave1 -> T-1
        const float* p = partials + (tt & (PDEPTH - 1)) * (NBLK * O_);
        float s = LD_RLX(&p[lane * O_ + bid]) + LD_RLX(&p[(lane + 64) * O_ + bid]);
        #pragma unroll
        for (int off = 32; off; off >>= 1) s += __shfl_xor(s, off);
        if (lane == 0) y[tt * O_ + bid] = s + bo[bid];
    }
}

extern "C" void kernel_launch(void* const* d_in, const int* in_sizes, int n_in,
                              void* d_out, int out_size, void* d_ws, size_t ws_size,
                              hipStream_t stream) {
    const float* inputs = (const float*)d_in[0];
    const float* W      = (const float*)d_in[1];
    const float* W_in   = (const float*)d_in[2];
    const float* b      = (const float*)d_in[3];
    const float* W_out  = (const float*)d_in[4];
    float* y  = (float*)d_out;

    // Workspace:
    //   [0, 64 KB)   arrival flags (NBLK x 64 B stride), zeroed per call
    //   [64 KB ...)  floats: xbuf[2N] | partials[PDEPTH*NBLK*O] | WoT[N*O]
    //                | bo[O] | vals[N*KELL] ; then u16 cols[N*KELL]
    unsigned* flags = (unsigned*)d_ws;
    float* fws      = (float*)((char*)d_ws + 64 * 1024);
    float* xbuf     = fws;
    float* partials = xbuf + 2 * N_;
    float* WoT      = partials + PDEPTH * NBLK * O_;
    float* bo       = WoT + N_ * O_;
    float* vals     = bo + O_;
    unsigned short* cols = (unsigned short*)(vals + (size_t)N_ * KELL);

    hipMemsetAsync(d_ws, 0, 64 * 1024, stream);   // reset barrier state

    hipLaunchKernelGGL(esn_prep, dim3((N_ * O_ + 255) / 256), dim3(256),
                       0, stream, W_out, WoT, bo);
    hipLaunchKernelGGL(esn_sparsify, dim3(N_), dim3(64),
                       0, stream, W, cols, vals);

    hipLaunchKernelGGL(esn_main, dim3(NBLK), dim3(NTHR), 0, stream,
                       inputs, cols, vals, W_in, b, WoT, bo, y,
                       flags, xbuf, partials);
}

// Round 8
// 13661.247 us; speedup vs baseline: 14.0009x; 1.2273x over previous
//
#include <hip/hip_runtime.h>

constexpr int N_ = 4096;
constexpr int D_ = 64;
constexpr int O_ = 64;
constexpr int T_ = 4096;
constexpr float LEAK_ = 0.8f;
constexpr int NBLK = 256;        // 1 block/CU, full machine; all co-resident
constexpr int NTHR = 1024;       // 16 waves
constexpr int NWAVE = 16;
constexpr int RPB = N_ / NBLK;   // 16 rows per block, ONE row per wave
constexpr int KELL = 512;        // ELL slots/row (max nnz ~485, 5-sigma margin)
constexpr int GRP = KELL / 64;   // 8 gather groups
constexpr int PDEPTH = 8;        // y-partials ring depth (skew-proof)
constexpr int SPT = N_ / NTHR;   // 4 x-slots per thread

typedef unsigned long long u64;
#define LD64(p)   __hip_atomic_load((const u64*)(p), __ATOMIC_RELAXED, __HIP_MEMORY_SCOPE_AGENT)
#define ST64(p,v) __hip_atomic_store((u64*)(p), (v), __ATOMIC_RELAXED, __HIP_MEMORY_SCOPE_AGENT)

__device__ __forceinline__ u64 mkpair(float x, unsigned seq) {
    return ((u64)seq << 32) | (u64)__float_as_uint(x);
}
__device__ __forceinline__ unsigned pseq(u64 v) { return (unsigned)(v >> 32); }
__device__ __forceinline__ float pval(u64 v) { return __uint_as_float((unsigned)v); }

// Prep A: transpose W_out weight part -> WoT[row][o], extract bias col bo.
__global__ void esn_prep(const float* __restrict__ W_out,
                         float* __restrict__ WoT, float* __restrict__ bo) {
    int idx = blockIdx.x * blockDim.x + threadIdx.x;
    if (idx < N_ * O_) {
        int row = idx / O_;
        int o = idx - row * O_;
        WoT[idx] = W_out[o * (N_ + 1) + row];
    }
    if (idx < O_) bo[idx] = W_out[idx * (N_ + 1) + N_];
}

// Prep B: dense W -> ELL with BANK-BALANCED slot assignment (bank = col & 31
// round-robined across the 8 slot-groups -> ~2-3-way conflicts, mostly free).
__global__ __launch_bounds__(64) void esn_sparsify(
    const float* __restrict__ W,
    unsigned short* __restrict__ cols, float* __restrict__ vals) {
    const int row = blockIdx.x;
    const int lane = threadIdx.x;
    __shared__ unsigned short nnz_c[KELL];
    __shared__ float nnz_w[KELL];
    __shared__ short slot_nnz[KELL];
    for (int s = lane; s < KELL; s += 64) slot_nnz[s] = -1;

    const float* Wr = W + (size_t)row * N_;
    const unsigned long long ltmask = (1ull << lane) - 1ull;
    int cnt = 0;
    for (int c0 = 0; c0 < N_; c0 += 64) {
        float w = Wr[c0 + lane];
        unsigned long long m = __ballot(w != 0.0f);
        if (w != 0.0f) {
            int pos = cnt + __popcll(m & ltmask);
            if (pos < KELL) { nnz_c[pos] = (unsigned short)(c0 + lane); nnz_w[pos] = w; }
        }
        cnt += __popcll(m);
    }
    if (cnt > KELL) cnt = KELL;
    __syncthreads();

    if (lane == 0) {
        unsigned char fill[GRP];
        unsigned char nxt[32];
        for (int g = 0; g < GRP; ++g) fill[g] = 0;
        for (int bnk = 0; bnk < 32; ++bnk) nxt[bnk] = 0;
        for (int i = 0; i < cnt; ++i) {
            int bnk = nnz_c[i] & 31;
            int g = nxt[bnk];
            int tries = 0;
            while (fill[g] >= 64 && tries < GRP) { g = (g + 1) % GRP; ++tries; }
            slot_nnz[g * 64 + fill[g]] = (short)i;
            fill[g]++;
            nxt[bnk] = (unsigned char)((g + 1) % GRP);
        }
    }
    __syncthreads();

    unsigned short* crow = cols + (size_t)row * KELL;
    float* vrow = vals + (size_t)row * KELL;
    for (int s = lane; s < KELL; s += 64) {
        int i = slot_nnz[s];
        crow[s] = (i >= 0) ? nnz_c[i] : 0;
        vrow[s] = (i >= 0) ? nnz_w[i] : 0.0f;
    }
}

__global__ __launch_bounds__(NTHR) void esn_main(
    const float* __restrict__ inputs,
    const unsigned short* __restrict__ cols, const float* __restrict__ vals,
    const float* __restrict__ W_in, const float* __restrict__ b,
    const float* __restrict__ WoT, const float* __restrict__ bo,
    float* __restrict__ y, u64* __restrict__ xpairs, u64* __restrict__ ppairs)
{
    __shared__ float x_lds[2][N_];          // 32 KB, double-buffered
    __shared__ float u_lds[2][D_];
    __shared__ float pw_lds[2][NWAVE][O_];  // 8 KB
    const int tid = threadIdx.x;
    const int bid = blockIdx.x;
    const int wave = tid >> 6;
    const int lane = tid & 63;
    const int row = bid * RPB + wave;       // this wave's row, for ALL 4096 steps

    // Hoist row-constant weights into registers (zero weight traffic in loop).
    unsigned short cc[GRP];
    float vv[GRP];
    #pragma unroll
    for (int j = 0; j < GRP; ++j) {
        cc[j] = cols[(size_t)row * KELL + 64 * j + lane];
        vv[j] = vals[(size_t)row * KELL + 64 * j + lane];
    }
    const float win  = W_in[row * D_ + lane];
    const float brow = b[row];
    const float wo   = WoT[row * O_ + lane];

    // Preamble: x(-1) = 0, u(0) staged.
    #pragma unroll
    for (int k = 0; k < SPT; ++k) x_lds[0][tid + k * NTHR] = 0.f;
    if (tid < D_) u_lds[0][tid] = inputs[tid];
    __syncthreads();

    float xo = 0.f;   // x_{t-1}[row], carried in-register (leak term)

    for (int t = 0; t < T_; ++t) {
        const int pt = t & 1;

        // Sparse gather from LDS + input fold + butterfly reduce.
        float acc = 0.f;
        #pragma unroll
        for (int j = 0; j < GRP; ++j) acc += vv[j] * x_lds[pt][cc[j]];
        acc += win * u_lds[pt][lane];
        #pragma unroll
        for (int off = 32; off; off >>= 1) acc += __shfl_xor(acc, off);
        float xn = (1.f - LEAK_) * xo + LEAK_ * tanhf(acc + brow);
        xo = xn;

        // Publish {xn, seq=t+1} atomically — single 8B store, no fence needed.
        if (lane == 0)
            ST64(&xpairs[(size_t)pt * N_ + row], mkpair(xn, (unsigned)(t + 1)));

        // Readout partial for own row; prefetch u(t+1).
        pw_lds[pt][wave][lane] = wo * xn;
        if (t + 1 < T_ && tid < D_) u_lds[pt ^ 1][tid] = inputs[(t + 1) * D_ + tid];

        // Poll x(t) pairs (4 slots/thread) and stage into x_lds[pt^1].
        {
            const u64* xp = xpairs + (size_t)pt * N_;
            const unsigned tgt = (unsigned)(t + 1);
            u64 v[SPT];
            #pragma unroll
            for (int k = 0; k < SPT; ++k) v[k] = LD64(&xp[tid + k * NTHR]);
            while (true) {
                int stale = 0;
                #pragma unroll
                for (int k = 0; k < SPT; ++k)
                    if (pseq(v[k]) != tgt) { v[k] = LD64(&xp[tid + k * NTHR]); stale = 1; }
                if (__ballot(stale) == 0ull) break;
            }
            #pragma unroll
            for (int k = 0; k < SPT; ++k)
                x_lds[pt ^ 1][tid + k * NTHR] = pval(v[k]);
        }
        __syncthreads();   // the ONLY sync per step

        // Post-sync roles (off the inter-block critical path).
        if (wave == 1) {
            // Block partial of y_t: sum 16 per-wave rows, publish with seq.
            float s = 0.f;
            #pragma unroll
            for (int w = 0; w < NWAVE; ++w) s += pw_lds[pt][w][lane];
            ST64(&ppairs[(size_t)(t & (PDEPTH - 1)) * (NBLK * O_) + bid * O_ + lane],
                 mkpair(s, (unsigned)(t + 1)));
        } else if (wave == 2 && t >= 2 && bid < O_) {
            // y(t-2): gather 256 block-partials for output o = bid.
            const u64* pp = ppairs + (size_t)((t - 2) & (PDEPTH - 1)) * (NBLK * O_);
            const unsigned tgt = (unsigned)(t - 1);
            u64 v0 = LD64(&pp[lane * O_ + bid]);
            u64 v1 = LD64(&pp[(lane + 64) * O_ + bid]);
            u64 v2 = LD64(&pp[(lane + 128) * O_ + bid]);
            u64 v3 = LD64(&pp[(lane + 192) * O_ + bid]);
            while (true) {
                int stale = 0;
                if (pseq(v0) != tgt) { v0 = LD64(&pp[lane * O_ + bid]); stale = 1; }
                if (pseq(v1) != tgt) { v1 = LD64(&pp[(lane + 64) * O_ + bid]); stale = 1; }
                if (pseq(v2) != tgt) { v2 = LD64(&pp[(lane + 128) * O_ + bid]); stale = 1; }
                if (pseq(v3) != tgt) { v3 = LD64(&pp[(lane + 192) * O_ + bid]); stale = 1; }
                if (__ballot(stale) == 0ull) break;
            }
            float s = pval(v0) + pval(v1) + pval(v2) + pval(v3);
            #pragma unroll
            for (int off = 32; off; off >>= 1) s += __shfl_xor(s, off);
            if (lane == 0) y[(t - 2) * O_ + bid] = s + bo[bid];
        }
    }

    // Drain y(T-2), y(T-1).
    if (wave == 2 && bid < O_) {
        for (int tt = T_ - 2; tt < T_; ++tt) {
            const u64* pp = ppairs + (size_t)(tt & (PDEPTH - 1)) * (NBLK * O_);
            const unsigned tgt = (unsigned)(tt + 1);
            u64 v0 = LD64(&pp[lane * O_ + bid]);
            u64 v1 = LD64(&pp[(lane + 64) * O_ + bid]);
            u64 v2 = LD64(&pp[(lane + 128) * O_ + bid]);
            u64 v3 = LD64(&pp[(lane + 192) * O_ + bid]);
            while (true) {
                int stale = 0;
                if (pseq(v0) != tgt) { v0 = LD64(&pp[lane * O_ + bid]); stale = 1; }
                if (pseq(v1) != tgt) { v1 = LD64(&pp[(lane + 64) * O_ + bid]); stale = 1; }
                if (pseq(v2) != tgt) { v2 = LD64(&pp[(lane + 128) * O_ + bid]); stale = 1; }
                if (pseq(v3) != tgt) { v3 = LD64(&pp[(lane + 192) * O_ + bid]); stale = 1; }
                if (__ballot(stale) == 0ull) break;
            }
            float s = pval(v0) + pval(v1) + pval(v2) + pval(v3);
            #pragma unroll
            for (int off = 32; off; off >>= 1) s += __shfl_xor(s, off);
            if (lane == 0) y[tt * O_ + bid] = s + bo[bid];
        }
    }
}

extern "C" void kernel_launch(void* const* d_in, const int* in_sizes, int n_in,
                              void* d_out, int out_size, void* d_ws, size_t ws_size,
                              hipStream_t stream) {
    const float* inputs = (const float*)d_in[0];
    const float* W      = (const float*)d_in[1];
    const float* W_in   = (const float*)d_in[2];
    const float* b      = (const float*)d_in[3];
    const float* W_out  = (const float*)d_in[4];
    float* y  = (float*)d_out;

    // Workspace:
    //   xpairs: 2 * N u64         (64 KB)   {x, seq} pairs, ping-pong
    //   ppairs: PDEPTH*NBLK*O u64 (1 MB)    {partial, seq} ring
    //   floats: WoT[N*O] | bo[O] | vals[N*KELL] ; then u16 cols[N*KELL]
    u64* xpairs = (u64*)d_ws;
    u64* ppairs = xpairs + 2 * N_;
    float* WoT  = (float*)(ppairs + (size_t)PDEPTH * NBLK * O_);
    float* bo   = WoT + N_ * O_;
    float* vals = bo + O_;
    unsigned short* cols = (unsigned short*)(vals + (size_t)N_ * KELL);

    // Zero all seq words (xpairs + ppairs) every call -> replay-deterministic.
    size_t seq_bytes = (2 * N_ + (size_t)PDEPTH * NBLK * O_) * sizeof(u64);
    hipMemsetAsync(d_ws, 0, seq_bytes, stream);

    hipLaunchKernelGGL(esn_prep, dim3((N_ * O_ + 255) / 256), dim3(256),
                       0, stream, W_out, WoT, bo);
    hipLaunchKernelGGL(esn_sparsify, dim3(N_), dim3(64),
                       0, stream, W, cols, vals);

    hipLaunchKernelGGL(esn_main, dim3(NBLK), dim3(NTHR), 0, stream,
                       inputs, cols, vals, W_in, b, WoT, bo, y,
                       xpairs, ppairs);
}